// Round 19
// baseline (318.670 us; speedup 1.0000x reference)
//
#include <hip/hip_runtime.h>
#include <cstdint>

#define NCLS 60
#define KC 512
#define DD 256
#define BB 32
#define NP 4096
#define LDP 260
#define EPS 1e-2f      // provable fp16-vs-np dist bound ~6.5e-3
#define PER_CLS 2048
#define ZBLOCKS (BB * (NP / 64))        // 2048
#define CBLOCKS ((NCLS * KC) / 64)      // 480

typedef _Float16 f16;
typedef _Float16 f16x8 __attribute__((ext_vector_type(8)));
typedef float f32x4 __attribute__((ext_vector_type(4)));
typedef float v2f __attribute__((ext_vector_type(2)));
typedef unsigned long long u64;

__device__ __forceinline__ float mul_rn_nofuse(float a, float b) {
  float p = a * b;
  asm("" : "+v"(p));
  return p;
}

// Packed fp32 mul/add: lanes bit-identical to scalar (validated rounds 5-8,16).
__device__ __forceinline__ v2f pk_mul(v2f a, v2f b) {
  v2f d;
  asm("v_pk_mul_f32 %0, %1, %2" : "=v"(d) : "v"(a), "v"(b));
  return d;
}
__device__ __forceinline__ v2f pk_add(v2f a, v2f b) {
  v2f d;
  asm("v_pk_add_f32 %0, %1, %2" : "=v"(d) : "v"(a), "v"(b));
  return d;
}

// One 128-half of numpy pairwise_sum of x*x (8-acc unrolled chain).
// numpy's 256-sum = chain(half0) + chain(half1); halves independent -> split
// across threads is bit-exact (validated r18).
__device__ __forceinline__ float np_pairwise128_sq(const float* a) {
  float r[8];
#pragma unroll
  for (int j = 0; j < 8; ++j) r[j] = mul_rn_nofuse(a[j], a[j]);
  for (int blk = 1; blk < 16; ++blk) {
#pragma unroll
    for (int j = 0; j < 8; ++j) {
      float p = mul_rn_nofuse(a[blk * 8 + j], a[blk * 8 + j]);
      r[j] = r[j] + p;
    }
  }
  return ((r[0] + r[1]) + (r[2] + r[3])) + ((r[4] + r[5]) + (r[6] + r[7]));
}

// ---- merged prep: blocks [0,2048) = z transpose+zsq; [2048,2528) = cb ----
__global__ __launch_bounds__(256) void vq_prep_kernel(
    const float* __restrict__ z, const float* __restrict__ emb,
    float* __restrict__ zsq, float* __restrict__ cbsq,
    f16* __restrict__ zT_h, f16* __restrict__ cb_h) {
  __shared__ float buf[64][LDP];   // 66.6 KB
  __shared__ float half2[64][2];
  const int t = threadIdx.x;

  if (blockIdx.x < ZBLOCKS) {
    const int b = blockIdx.x >> 6;
    const int n0 = (blockIdx.x & 63) * 64;
    const float* zb = z + (size_t)b * DD * NP;
    const int n = t & 63, dq = t >> 6;
#pragma unroll 4
    for (int it = 0; it < 64; ++it) {
      int d = it * 4 + dq;
      buf[n][d] = zb[(size_t)d * NP + n0 + n];   // coalesced over n
    }
    __syncthreads();
    f16* ob = zT_h + ((size_t)b * NP + n0) * DD;
#pragma unroll
    for (int it = 0; it < 16; ++it) {
      int row = it * 4 + dq;
      union { f16 h[4]; uint2 u; } pk;
#pragma unroll
      for (int j = 0; j < 4; ++j) pk.h[j] = (f16)buf[row][n * 4 + j];
      *(uint2*)&ob[(size_t)row * DD + n * 4] = pk.u;
    }
    if (t < 128) {
      int r = t & 63, h = t >> 6;
      half2[r][h] = np_pairwise128_sq(&buf[r][h * 128]);
    }
    __syncthreads();
    if (t < 64) zsq[b * NP + n0 + t] = half2[t][0] + half2[t][1];
  } else {
    const int r0 = (blockIdx.x - ZBLOCKS) * 64;
    const float4* e4 = (const float4*)emb;
#pragma unroll
    for (int i = 0; i < 16; ++i) {
      int flat = i * 256 + t;
      int row = flat >> 6, col4 = flat & 63;
      *(float4*)&buf[row][col4 * 4] = e4[(size_t)(r0 + row) * 64 + col4];
    }
    __syncthreads();
    if (t < 128) {
      int r = t & 63, h = t >> 6;
      half2[r][h] = np_pairwise128_sq(&buf[r][h * 128]);
    }
#pragma unroll
    for (int i = 0; i < 16; ++i) {
      int flat = i * 256 + t;
      int row = flat >> 6, q4 = flat & 63;
      union { f16 h[4]; uint2 u; } pk;
#pragma unroll
      for (int j = 0; j < 4; ++j) pk.h[j] = (f16)buf[row][q4 * 4 + j];
      *(uint2*)&cb_h[(size_t)(r0 + row) * DD + q4 * 4] = pk.u;
    }
    __syncthreads();
    if (t < 64) cbsq[r0 + t] = half2[t][0] + half2[t][1];
  }
}

// ---- phase 1: fp16 MFMA + top-2; z RESIDENT in LDS; XCD-swizzled grid ----
// 1D grid 2048. id -> xcd=id&7, j=id>>3, b=xcd*4+(j>>6), n0=(j&63)*64: with
// round-robin id%8 dispatch each XCD serves only batches 4x..4x+3, so the hot
// class codebooks (<=1MB fp16) stay L2-resident instead of thrashing (8MB/4MB).
__global__ __launch_bounds__(256) void vq_mfma_kernel(
    const f16* __restrict__ zT_h, const int* __restrict__ c,
    const f16* __restrict__ cb_h, const float* __restrict__ cbsq,
    int* __restrict__ idx_out, unsigned int* __restrict__ counters,
    unsigned int* __restrict__ lists) {
  __shared__ __align__(16) f16 zs[64][264];   // 33.8 KB, resident
  __shared__ __align__(16) f16 cs[128][72];   // 18.4 KB, cycled per phase
  const int t = threadIdx.x;
  const int id = blockIdx.x;
  const int xcd = id & 7;
  const int j = id >> 3;
  const int b = xcd * 4 + (j >> 6);
  const int n0 = (j & 63) * 64;
  const int wave = t >> 6;
  const int wm = wave >> 1, wn = wave & 1;
  const int l = t & 63, lr = l & 15, lg = l >> 4;
  const int cls = c[b];
  const f16* __restrict__ zTb = zT_h + ((size_t)b * NP + n0) * DD;
  const f16* __restrict__ cbb = cb_h + (size_t)cls * KC * DD;
  const float* __restrict__ cbsqb = cbsq + cls * KC;
  const int crow0 = t >> 3, cseg = (t & 7) * 8;

#define LOADC(q)                                                               \
  do {                                                                         \
    const int kn_ = (q) >> 2, dn_ = (q) & 3;                                   \
    const f16* p_ = cbb + ((size_t)(kn_ * 128 + crow0)) * DD + dn_ * 64 + cseg;\
    rc0 = *(const f16x8*)(p_);                                                 \
    rc1 = *(const f16x8*)(p_ + (size_t)32 * DD);                               \
    rc2 = *(const f16x8*)(p_ + (size_t)64 * DD);                               \
    rc3 = *(const f16x8*)(p_ + (size_t)96 * DD);                               \
  } while (0)

#define WRITEC()                                                               \
  do {                                                                         \
    *(f16x8*)&cs[crow0][cseg] = rc0;                                           \
    *(f16x8*)&cs[crow0 + 32][cseg] = rc1;                                      \
    *(f16x8*)&cs[crow0 + 64][cseg] = rc2;                                      \
    *(f16x8*)&cs[crow0 + 96][cseg] = rc3;                                      \
  } while (0)

  // stage z tile [64 n][256 d] once
#pragma unroll
  for (int i = 0; i < 8; ++i) {
    int flat = i * 256 + t;
    int row = flat >> 5, seg = flat & 31;
    *(f16x8*)&zs[row][seg * 8] = *(const f16x8*)&zTb[(size_t)row * DD + seg * 8];
  }

  float m1[8], m2[8];
  int i1[8];
#pragma unroll
  for (int r = 0; r < 8; ++r) { m1[r] = 3.4e38f; m2[r] = 3.4e38f; i1[r] = 0; }

  f32x4 acc[2][4];
#pragma unroll
  for (int mi = 0; mi < 2; ++mi)
#pragma unroll
    for (int nj = 0; nj < 4; ++nj) acc[mi][nj] = (f32x4){0.f, 0.f, 0.f, 0.f};

  f16x8 rc0, rc1, rc2, rc3;
  LOADC(0);
  __syncthreads();
  WRITEC();
  __syncthreads();

#pragma unroll 1
  for (int p = 0; p < 16; ++p) {
    if (p < 15) LOADC(p + 1);   // in flight during compute
    const int dzb = (p & 3) * 64;
#pragma unroll
    for (int s = 0; s < 2; ++s) {
      const int dz = dzb + s * 32 + lg * 8;
      const int dcs = s * 32 + lg * 8;
      f16x8 af[2], bf[4];
#pragma unroll
      for (int mi = 0; mi < 2; ++mi)
        af[mi] = *(const f16x8*)&zs[wm * 32 + mi * 16 + lr][dz];
#pragma unroll
      for (int nj = 0; nj < 4; ++nj)
        bf[nj] = *(const f16x8*)&cs[wn * 64 + nj * 16 + lr][dcs];
#pragma unroll
      for (int mi = 0; mi < 2; ++mi)
#pragma unroll
        for (int nj = 0; nj < 4; ++nj)
          acc[mi][nj] = __builtin_amdgcn_mfma_f32_16x16x32_f16(
              af[mi], bf[nj], acc[mi][nj], 0, 0, 0);
    }
    if ((p & 3) == 3) {  // kt complete: dist (zsq constant per row) + top-2
      const int kt = p >> 2;
#pragma unroll
      for (int nj = 0; nj < 4; ++nj) {
        const int k = kt * 128 + wn * 64 + nj * 16 + lr;
        const float cq = cbsqb[k];
#pragma unroll
        for (int mi = 0; mi < 2; ++mi)
#pragma unroll
          for (int rg = 0; rg < 4; ++rg) {
            const int ri = mi * 4 + rg;
            float dist = fmaf(-2.0f, acc[mi][nj][rg], cq);
            if (dist < m1[ri]) {
              m2[ri] = m1[ri]; m1[ri] = dist; i1[ri] = k;
            } else if (dist < m2[ri]) {
              m2[ri] = dist;
            }
          }
      }
#pragma unroll
      for (int mi = 0; mi < 2; ++mi)
#pragma unroll
        for (int nj = 0; nj < 4; ++nj) acc[mi][nj] = (f32x4){0.f, 0.f, 0.f, 0.f};
    }
    __syncthreads();
    if (p < 15) {
      WRITEC();
      __syncthreads();
    }
  }

#pragma unroll
  for (int r = 0; r < 8; ++r) {
#pragma unroll
    for (int off = 8; off >= 1; off >>= 1) {
      float om1 = __shfl_xor(m1[r], off);
      float om2 = __shfl_xor(m2[r], off);
      int oi = __shfl_xor(i1[r], off);
      bool take = (om1 < m1[r]) || (om1 == m1[r] && oi < i1[r]);
      if (take) {
        m2[r] = fminf(m1[r], om2);
        m1[r] = om1;
        i1[r] = oi;
      } else {
        m2[r] = fminf(m2[r], om1);
      }
    }
  }

  float* redm = (float*)&zs[0][0];
  int* redi = (int*)&cs[0][0];
  if (lr == 0) {
#pragma unroll
    for (int r = 0; r < 8; ++r) {
      int row = wm * 32 + (r >> 2) * 16 + lg * 4 + (r & 3);
      redm[(wn * 64 + row) * 2 + 0] = m1[r];
      redm[(wn * 64 + row) * 2 + 1] = m2[r];
      redi[wn * 64 + row] = i1[r];
    }
  }
  __syncthreads();
  if (t < 64) {
    const int row = t;
    float a1 = redm[row * 2], a2 = redm[row * 2 + 1];
    int ai = redi[row];
    float b1 = redm[(64 + row) * 2], b2 = redm[(64 + row) * 2 + 1];
    int bi2 = redi[64 + row];
    float f1, f2;
    int idx;
    if (b1 < a1) { f1 = b1; idx = bi2; f2 = fminf(a1, b2); }
    else { f1 = a1; idx = ai; f2 = fminf(b1, a2); }
    const int n = n0 + row;
    idx_out[b * NP + n] = idx;
    if (f2 - f1 < EPS) {
      unsigned p = atomicAdd(&counters[cls], 1u);
      if (p < PER_CLS) lists[cls * PER_CLS + p] = ((unsigned)b << 12) | (unsigned)n;
    }
  }
#undef LOADC
#undef WRITEC
}

// ---- phase 2: np-exact fixup, k-split x8, pk-packed chains (r16 verbatim) --
__global__ __launch_bounds__(256) void vq_fix_kernel(
    const float* __restrict__ z, const float* __restrict__ emb,
    const float* __restrict__ zsq, const float* __restrict__ cbsq,
    u64* __restrict__ best_g, const unsigned int* __restrict__ counters,
    const unsigned int* __restrict__ lists) {
  const int cls = blockIdx.x;
  unsigned cnt = counters[cls];
  if (cnt > PER_CLS) cnt = PER_CLS;
  const int grp = blockIdx.y >> 3;
  const int kz = blockIdx.y & 7;
  const unsigned base = grp * 32;
  if (base >= cnt) return;
  const int t = threadIdx.x;

  __shared__ float zrow[32][LDP];
  __shared__ float cbt[32][LDP];
  __shared__ float zq[32];
  __shared__ unsigned bn[32];
  __shared__ float red_v[256];
  __shared__ int red_k[256];

  if (t < 32) {
    unsigned p = base + t;
    unsigned e = (p < cnt) ? lists[cls * PER_CLS + p] : 0xFFFFFFFFu;
    bn[t] = e;
    zq[t] = (e != 0xFFFFFFFFu) ? zsq[(e >> 12) * NP + (e & (NP - 1))] : 0.f;
  }
  __syncthreads();
  {
    int r = t >> 3, d0 = t & 7;
    unsigned e = bn[r];
    if (e != 0xFFFFFFFFu) {
      int bb = (int)(e >> 12), nn = (int)(e & (NP - 1));
      const float* zp = z + (size_t)bb * DD * NP + nn;
#pragma unroll
      for (int j = 0; j < 32; ++j) zrow[r][d0 + j * 8] = zp[(size_t)(d0 + j * 8) * NP];
    }
  }

  const int pg = t & 15;
  const int kg = t >> 4;
  const bool val0 = (bn[pg] != 0xFFFFFFFFu);
  const bool val1 = (bn[pg + 16] != 0xFFFFFFFFu);
  float best[2] = {3.4e38f, 3.4e38f};
  int bk[2] = {0x7FFFFFFF, 0x7FFFFFFF};

#pragma unroll 1
  for (int tt = 0; tt < 2; ++tt) {
    const int tile = kz * 2 + tt;
    __syncthreads();
#pragma unroll
    for (int j = 0; j < 8; ++j) {
      int flat = j * 256 + t;
      int row = flat >> 6, col4 = flat & 63;
      *(float4*)&cbt[row][col4 * 4] =
          *(const float4*)&emb[((size_t)cls * KC + tile * 32 + row) * DD + col4 * 4];
    }
    __syncthreads();

    v2f A2[2][2][2];
#pragma unroll
    for (int ps = 0; ps < 2; ++ps)
#pragma unroll
      for (int ks = 0; ks < 2; ++ks) {
        A2[ps][ks][0] = (v2f){0.f, 0.f};
        A2[ps][ks][1] = (v2f){0.f, 0.f};
      }

#pragma unroll 1
    for (int c16 = 0; c16 < 16; ++c16) {
      v2f za2[2][8], ca2[2][8];
#pragma unroll
      for (int q = 0; q < 4; ++q) {
        float4 z0 = *(const float4*)&zrow[pg][c16 * 16 + q * 4];
        float4 z1 = *(const float4*)&zrow[pg + 16][c16 * 16 + q * 4];
        float4 c0 = *(const float4*)&cbt[kg][c16 * 16 + q * 4];
        float4 c1 = *(const float4*)&cbt[kg + 16][c16 * 16 + q * 4];
        za2[0][q * 2 + 0] = (v2f){z0.x, z0.y};
        za2[0][q * 2 + 1] = (v2f){z0.z, z0.w};
        za2[1][q * 2 + 0] = (v2f){z1.x, z1.y};
        za2[1][q * 2 + 1] = (v2f){z1.z, z1.w};
        ca2[0][q * 2 + 0] = (v2f){c0.x, c0.y};
        ca2[0][q * 2 + 1] = (v2f){c0.z, c0.w};
        ca2[1][q * 2 + 0] = (v2f){c1.x, c1.y};
        ca2[1][q * 2 + 1] = (v2f){c1.z, c1.w};
      }
#pragma unroll
      for (int s = 3; s >= 0; --s)
#pragma unroll
        for (int ps = 0; ps < 2; ++ps)
#pragma unroll
          for (int ks = 0; ks < 2; ++ks) {
            A2[ps][ks][0] =
                pk_add(pk_mul(za2[ps][s * 2 + 0], ca2[ks][s * 2 + 0]), A2[ps][ks][0]);
            A2[ps][ks][1] =
                pk_add(pk_mul(za2[ps][s * 2 + 1], ca2[ks][s * 2 + 1]), A2[ps][ks][1]);
          }
    }

#pragma unroll
    for (int ps = 0; ps < 2; ++ps) {
      const float zqv = zq[pg + 16 * ps];
#pragma unroll
      for (int ks = 0; ks < 2; ++ks) {
        const int k = tile * 32 + kg + 16 * ks;
        float dot = (A2[ps][ks][0].x + A2[ps][ks][0].y) +
                    (A2[ps][ks][1].x + A2[ps][ks][1].y);
        float dist = (zqv - 2.0f * dot) + cbsq[cls * KC + k];
        if (dist < best[ps]) { best[ps] = dist; bk[ps] = k; }
      }
    }
  }

#pragma unroll
  for (int s = 0; s < 2; ++s) {
    __syncthreads();
    red_v[t] = best[s];
    red_k[t] = bk[s];
    __syncthreads();
    for (int off = 8; off >= 1; off >>= 1) {
      if (kg < off) {
        int o = t + 16 * off;
        float ov = red_v[o];
        int ok = red_k[o];
        if (ov < red_v[t] || (ov == red_v[t] && ok < red_k[t])) {
          red_v[t] = ov;
          red_k[t] = ok;
        }
      }
      __syncthreads();
    }
    if (kg == 0 && ((s == 0 && val0) || (s == 1 && val1))) {
      unsigned e = bn[pg + 16 * s];
      unsigned u = __float_as_uint(red_v[t]);
      u = (u & 0x80000000u) ? ~u : (u | 0x80000000u);
      u64 pkd = ((u64)u << 32) | (unsigned)red_k[t];
      atomicMin(&best_g[(e >> 12) * NP + (e & (NP - 1))], pkd);
    }
  }
}

// ---- commit: unpack merged best into idx (flagged entries only) ----
__global__ __launch_bounds__(256) void vq_commit_kernel(
    const u64* __restrict__ best_g, const unsigned int* __restrict__ counters,
    const unsigned int* __restrict__ lists, int* __restrict__ idx_out) {
  const int cls = blockIdx.x;
  unsigned cnt = counters[cls];
  if (cnt > PER_CLS) cnt = PER_CLS;
  for (unsigned i = threadIdx.x; i < cnt; i += 256) {
    unsigned e = lists[cls * PER_CLS + i];
    int pos = (int)(e >> 12) * NP + (int)(e & (NP - 1));
    u64 v = best_g[pos];
    if (v != ~0ull) idx_out[pos] = (int)(unsigned)(v & 0xFFFFFFFFu);
  }
}

// ---- gather selected rows -> [B,H,W,D] (bitwise copy; overwrites d_out) ----
__global__ __launch_bounds__(256) void vq_gather_kernel(
    const int* __restrict__ c, const float* __restrict__ emb,
    const int* __restrict__ idx, float* __restrict__ out) {
  int t = threadIdx.x;
  int r = blockIdx.x * 4 + (t >> 6);
  int lane = t & 63;
  int b = r >> 12;
  int k = idx[r];
  const float4* src = (const float4*)(emb + (size_t)(c[b] * KC + k) * DD);
  float4* dst = (float4*)(out + (size_t)r * DD);
  dst[lane] = src[lane];
}

extern "C" void kernel_launch(void* const* d_in, const int* in_sizes, int n_in,
                              void* d_out, int out_size, void* d_ws, size_t ws_size,
                              hipStream_t stream) {
  const float* z = (const float*)d_in[0];    // [32,256,64,64]
  const int* c = (const int*)d_in[1];        // [32]
  const float* emb = (const float*)d_in[2];  // [30720,256]
  float* out = (float*)d_out;                // [32,64,64,256] = 134.2 MB

  char* ws = (char*)d_ws;
  float* zsq = (float*)ws;                                   // 512 KB
  float* cbsq = (float*)(ws + 524288);                       // 120 KB
  int* idx = (int*)(ws + 655360);                            // 512 KB
  unsigned int* counters = (unsigned int*)(ws + 1179648);    // 256 B
  unsigned int* lists = (unsigned int*)(ws + 1179904);       // 480 KB

  // d_out spare: zT_h (67.1 MB) + cb_h (15.7 MB) + best_g (1 MB); gather
  // fully overwrites d_out last.
  f16* zT_h = (f16*)d_out;
  f16* cb_h = (f16*)((char*)d_out + (size_t)BB * NP * DD * 2);
  u64* best_g = (u64*)((char*)d_out + 82837504);

  hipMemsetAsync(counters, 0, NCLS * sizeof(unsigned int), stream);
  hipMemsetAsync(best_g, 0xFF, (size_t)BB * NP * 8, stream);
  vq_prep_kernel<<<ZBLOCKS + CBLOCKS, 256, 0, stream>>>(z, emb, zsq, cbsq, zT_h, cb_h);
  vq_mfma_kernel<<<ZBLOCKS, 256, 0, stream>>>(zT_h, c, cb_h, cbsq, idx, counters, lists);
  dim3 gF(NCLS, (PER_CLS / 32) * 8);
  vq_fix_kernel<<<gF, 256, 0, stream>>>(z, emb, zsq, cbsq, best_g, counters, lists);
  vq_commit_kernel<<<NCLS, 256, 0, stream>>>(best_g, counters, lists, idx);
  vq_gather_kernel<<<(BB * NP) / 4, 256, 0, stream>>>(c, emb, idx, out);
}

// Round 20
// 310.261 us; speedup vs baseline: 1.0271x; 1.0271x over previous
//
#include <hip/hip_runtime.h>
#include <cstdint>

#define NCLS 60
#define KC 512
#define DD 256
#define BB 32
#define NP 4096
#define LDP 260
#define EPS 1e-2f      // provable fp16-vs-np dist bound ~6.5e-3
#define PER_CLS 2048
#define ZBLOCKS (BB * (NP / 64))        // 2048
#define CBLOCKS ((NCLS * KC) / 64)      // 480

typedef _Float16 f16;
typedef _Float16 f16x8 __attribute__((ext_vector_type(8)));
typedef float f32x4 __attribute__((ext_vector_type(4)));
typedef float v2f __attribute__((ext_vector_type(2)));
typedef unsigned long long u64;

__device__ __forceinline__ float mul_rn_nofuse(float a, float b) {
  float p = a * b;
  asm("" : "+v"(p));
  return p;
}

// Packed fp32 mul/add: lanes bit-identical to scalar (validated rounds 5-8,16).
__device__ __forceinline__ v2f pk_mul(v2f a, v2f b) {
  v2f d;
  asm("v_pk_mul_f32 %0, %1, %2" : "=v"(d) : "v"(a), "v"(b));
  return d;
}
__device__ __forceinline__ v2f pk_add(v2f a, v2f b) {
  v2f d;
  asm("v_pk_add_f32 %0, %1, %2" : "=v"(d) : "v"(a), "v"(b));
  return d;
}

// One 128-half of numpy pairwise_sum of x*x (8-acc unrolled chain).
__device__ __forceinline__ float np_pairwise128_sq(const float* a) {
  float r[8];
#pragma unroll
  for (int j = 0; j < 8; ++j) r[j] = mul_rn_nofuse(a[j], a[j]);
  for (int blk = 1; blk < 16; ++blk) {
#pragma unroll
    for (int j = 0; j < 8; ++j) {
      float p = mul_rn_nofuse(a[blk * 8 + j], a[blk * 8 + j]);
      r[j] = r[j] + p;
    }
  }
  return ((r[0] + r[1]) + (r[2] + r[3])) + ((r[4] + r[5]) + (r[6] + r[7]));
}

// ---- merged prep: blocks [0,2048) = z transpose+zsq; [2048,2528) = cb ----
__global__ __launch_bounds__(256) void vq_prep_kernel(
    const float* __restrict__ z, const float* __restrict__ emb,
    float* __restrict__ zsq, float* __restrict__ cbsq,
    f16* __restrict__ zT_h, f16* __restrict__ cb_h) {
  __shared__ float buf[64][LDP];   // 66.6 KB
  __shared__ float half2[64][2];
  const int t = threadIdx.x;

  if (blockIdx.x < ZBLOCKS) {
    const int b = blockIdx.x >> 6;
    const int n0 = (blockIdx.x & 63) * 64;
    const float* zb = z + (size_t)b * DD * NP;
    const int n = t & 63, dq = t >> 6;
#pragma unroll 4
    for (int it = 0; it < 64; ++it) {
      int d = it * 4 + dq;
      buf[n][d] = zb[(size_t)d * NP + n0 + n];   // coalesced over n
    }
    __syncthreads();
    f16* ob = zT_h + ((size_t)b * NP + n0) * DD;
#pragma unroll
    for (int it = 0; it < 16; ++it) {
      int row = it * 4 + dq;
      union { f16 h[4]; uint2 u; } pk;
#pragma unroll
      for (int j = 0; j < 4; ++j) pk.h[j] = (f16)buf[row][n * 4 + j];
      *(uint2*)&ob[(size_t)row * DD + n * 4] = pk.u;
    }
    if (t < 128) {
      int r = t & 63, h = t >> 6;
      half2[r][h] = np_pairwise128_sq(&buf[r][h * 128]);
    }
    __syncthreads();
    if (t < 64) zsq[b * NP + n0 + t] = half2[t][0] + half2[t][1];
  } else {
    const int r0 = (blockIdx.x - ZBLOCKS) * 64;
    const float4* e4 = (const float4*)emb;
#pragma unroll
    for (int i = 0; i < 16; ++i) {
      int flat = i * 256 + t;
      int row = flat >> 6, col4 = flat & 63;
      *(float4*)&buf[row][col4 * 4] = e4[(size_t)(r0 + row) * 64 + col4];
    }
    __syncthreads();
    if (t < 128) {
      int r = t & 63, h = t >> 6;
      half2[r][h] = np_pairwise128_sq(&buf[r][h * 128]);
    }
#pragma unroll
    for (int i = 0; i < 16; ++i) {
      int flat = i * 256 + t;
      int row = flat >> 6, q4 = flat & 63;
      union { f16 h[4]; uint2 u; } pk;
#pragma unroll
      for (int j = 0; j < 4; ++j) pk.h[j] = (f16)buf[row][q4 * 4 + j];
      *(uint2*)&cb_h[(size_t)(r0 + row) * DD + q4 * 4] = pk.u;
    }
    __syncthreads();
    if (t < 64) cbsq[r0 + t] = half2[t][0] + half2[t][1];
  }
}

// ---- phase 1: fp16 MFMA + top-2; z in REGISTERS, cs double-buffered ----
// Per thread: zf[2][8] A-fragments (64 VGPR, statically indexed). Phase
// (kt,dc): compute from cs[dc&1] (8 bf reads + 16 MFMA), write next chunk to
// cs[(dc&1)^1], ONE barrier. Writer-target's readers finished at previous
// phase's barrier -> race-free with a single barrier per phase.
__global__ __launch_bounds__(256) void vq_mfma_kernel(
    const f16* __restrict__ zT_h, const int* __restrict__ c,
    const f16* __restrict__ cb_h, const float* __restrict__ cbsq,
    int* __restrict__ idx_out, unsigned int* __restrict__ counters,
    unsigned int* __restrict__ lists) {
  __shared__ __align__(16) f16 cs[2][128][72];   // 36.9 KB total
  const int t = threadIdx.x;
  const int id = blockIdx.x;
  const int xcd = id & 7;
  const int j = id >> 3;
  const int b = xcd * 4 + (j >> 6);
  const int n0 = (j & 63) * 64;
  const int wave = t >> 6;
  const int wm = wave >> 1, wn = wave & 1;
  const int l = t & 63, lr = l & 15, lg = l >> 4;
  const int cls = c[b];
  const f16* __restrict__ zTb = zT_h + ((size_t)b * NP + n0) * DD;
  const f16* __restrict__ cbb = cb_h + (size_t)cls * KC * DD;
  const float* __restrict__ cbsqb = cbsq + cls * KC;
  const int crow0 = t >> 3, cseg = (t & 7) * 8;

#define LOADC(q)                                                               \
  do {                                                                         \
    const int kn_ = (q) >> 2, dn_ = (q) & 3;                                   \
    const f16* p_ = cbb + ((size_t)(kn_ * 128 + crow0)) * DD + dn_ * 64 + cseg;\
    rc0 = *(const f16x8*)(p_);                                                 \
    rc1 = *(const f16x8*)(p_ + (size_t)32 * DD);                               \
    rc2 = *(const f16x8*)(p_ + (size_t)64 * DD);                               \
    rc3 = *(const f16x8*)(p_ + (size_t)96 * DD);                               \
  } while (0)

#define WRITEC(B)                                                              \
  do {                                                                         \
    *(f16x8*)&cs[B][crow0][cseg] = rc0;                                        \
    *(f16x8*)&cs[B][crow0 + 32][cseg] = rc1;                                   \
    *(f16x8*)&cs[B][crow0 + 64][cseg] = rc2;                                   \
    *(f16x8*)&cs[B][crow0 + 96][cseg] = rc3;                                   \
  } while (0)

  // z A-fragments into registers: zf[mi][ks] = zT[row][ks*32 + lg*8 .. +8),
  // row = wm*32 + mi*16 + lr. Identical bytes to the old zs LDS read.
  f16x8 zf[2][8];
#pragma unroll
  for (int mi = 0; mi < 2; ++mi) {
    const f16* zr = zTb + (size_t)(wm * 32 + mi * 16 + lr) * DD + lg * 8;
#pragma unroll
    for (int ks = 0; ks < 8; ++ks) zf[mi][ks] = *(const f16x8*)(zr + ks * 32);
  }

  float m1[8], m2[8];
  int i1[8];
#pragma unroll
  for (int r = 0; r < 8; ++r) { m1[r] = 3.4e38f; m2[r] = 3.4e38f; i1[r] = 0; }

  f32x4 acc[2][4];
#pragma unroll
  for (int mi = 0; mi < 2; ++mi)
#pragma unroll
    for (int nj = 0; nj < 4; ++nj) acc[mi][nj] = (f32x4){0.f, 0.f, 0.f, 0.f};

  f16x8 rc0, rc1, rc2, rc3;
  LOADC(0);
  WRITEC(0);
  __syncthreads();

#pragma unroll 1
  for (int kt = 0; kt < 4; ++kt) {
#pragma unroll
    for (int dc = 0; dc < 4; ++dc) {
      const int q = kt * 4 + dc;          // phase index; q&1 == dc&1
      const int buf = dc & 1;             // compile-time
      if (kt < 3 || dc < 3) LOADC(q + 1); // next chunk, in flight over compute
#pragma unroll
      for (int s = 0; s < 2; ++s) {
        const int dcs = s * 32 + lg * 8;
        f16x8 bf[4];
#pragma unroll
        for (int nj = 0; nj < 4; ++nj)
          bf[nj] = *(const f16x8*)&cs[buf][wn * 64 + nj * 16 + lr][dcs];
#pragma unroll
        for (int mi = 0; mi < 2; ++mi)
#pragma unroll
          for (int nj = 0; nj < 4; ++nj)
            acc[mi][nj] = __builtin_amdgcn_mfma_f32_16x16x32_f16(
                zf[mi][dc * 2 + s], bf[nj], acc[mi][nj], 0, 0, 0);
      }
      if (dc == 3) {  // kt complete: dist (zsq constant per row) + top-2
#pragma unroll
        for (int nj = 0; nj < 4; ++nj) {
          const int k = kt * 128 + wn * 64 + nj * 16 + lr;
          const float cq = cbsqb[k];
#pragma unroll
          for (int mi = 0; mi < 2; ++mi)
#pragma unroll
            for (int rg = 0; rg < 4; ++rg) {
              const int ri = mi * 4 + rg;
              float dist = fmaf(-2.0f, acc[mi][nj][rg], cq);
              if (dist < m1[ri]) {
                m2[ri] = m1[ri]; m1[ri] = dist; i1[ri] = k;
              } else if (dist < m2[ri]) {
                m2[ri] = dist;
              }
            }
        }
#pragma unroll
        for (int mi = 0; mi < 2; ++mi)
#pragma unroll
          for (int nj = 0; nj < 4; ++nj)
            acc[mi][nj] = (f32x4){0.f, 0.f, 0.f, 0.f};
      }
      if (kt < 3 || dc < 3) WRITEC(buf ^ 1);  // other buffer; its readers done
      __syncthreads();                         // single barrier per phase
    }
  }

  // top-2 butterfly across the 16 lanes (lr) sharing each row set
#pragma unroll
  for (int r = 0; r < 8; ++r) {
#pragma unroll
    for (int off = 8; off >= 1; off >>= 1) {
      float om1 = __shfl_xor(m1[r], off);
      float om2 = __shfl_xor(m2[r], off);
      int oi = __shfl_xor(i1[r], off);
      bool take = (om1 < m1[r]) || (om1 == m1[r] && oi < i1[r]);
      if (take) {
        m2[r] = fminf(m1[r], om2);
        m1[r] = om1;
        i1[r] = oi;
      } else {
        m2[r] = fminf(m2[r], om1);
      }
    }
  }

  // cross-wave (wn halves) merge via LDS overlay on cs (dead after last phase)
  float* redm = (float*)&cs[0][0][0];   // [2][64][2] floats
  int* redi = (int*)&cs[1][0][0];       // [2][64] ints
  if (lr == 0) {
#pragma unroll
    for (int r = 0; r < 8; ++r) {
      int row = wm * 32 + (r >> 2) * 16 + lg * 4 + (r & 3);
      redm[(wn * 64 + row) * 2 + 0] = m1[r];
      redm[(wn * 64 + row) * 2 + 1] = m2[r];
      redi[wn * 64 + row] = i1[r];
    }
  }
  __syncthreads();
  if (t < 64) {
    const int row = t;
    float a1 = redm[row * 2], a2 = redm[row * 2 + 1];
    int ai = redi[row];
    float b1 = redm[(64 + row) * 2], b2 = redm[(64 + row) * 2 + 1];
    int bi2 = redi[64 + row];
    float f1, f2;
    int idx;
    if (b1 < a1) { f1 = b1; idx = bi2; f2 = fminf(a1, b2); }
    else { f1 = a1; idx = ai; f2 = fminf(b1, a2); }
    const int n = n0 + row;
    idx_out[b * NP + n] = idx;
    if (f2 - f1 < EPS) {
      unsigned p = atomicAdd(&counters[cls], 1u);
      if (p < PER_CLS) lists[cls * PER_CLS + p] = ((unsigned)b << 12) | (unsigned)n;
    }
  }
#undef LOADC
#undef WRITEC
}

// ---- phase 2: np-exact fixup, k-split x8, pk-packed chains (r16 verbatim) --
__global__ __launch_bounds__(256) void vq_fix_kernel(
    const float* __restrict__ z, const float* __restrict__ emb,
    const float* __restrict__ zsq, const float* __restrict__ cbsq,
    u64* __restrict__ best_g, const unsigned int* __restrict__ counters,
    const unsigned int* __restrict__ lists) {
  const int cls = blockIdx.x;
  unsigned cnt = counters[cls];
  if (cnt > PER_CLS) cnt = PER_CLS;
  const int grp = blockIdx.y >> 3;
  const int kz = blockIdx.y & 7;
  const unsigned base = grp * 32;
  if (base >= cnt) return;
  const int t = threadIdx.x;

  __shared__ float zrow[32][LDP];
  __shared__ float cbt[32][LDP];
  __shared__ float zq[32];
  __shared__ unsigned bn[32];
  __shared__ float red_v[256];
  __shared__ int red_k[256];

  if (t < 32) {
    unsigned p = base + t;
    unsigned e = (p < cnt) ? lists[cls * PER_CLS + p] : 0xFFFFFFFFu;
    bn[t] = e;
    zq[t] = (e != 0xFFFFFFFFu) ? zsq[(e >> 12) * NP + (e & (NP - 1))] : 0.f;
  }
  __syncthreads();
  {
    int r = t >> 3, d0 = t & 7;
    unsigned e = bn[r];
    if (e != 0xFFFFFFFFu) {
      int bb = (int)(e >> 12), nn = (int)(e & (NP - 1));
      const float* zp = z + (size_t)bb * DD * NP + nn;
#pragma unroll
      for (int j = 0; j < 32; ++j) zrow[r][d0 + j * 8] = zp[(size_t)(d0 + j * 8) * NP];
    }
  }

  const int pg = t & 15;
  const int kg = t >> 4;
  const bool val0 = (bn[pg] != 0xFFFFFFFFu);
  const bool val1 = (bn[pg + 16] != 0xFFFFFFFFu);
  float best[2] = {3.4e38f, 3.4e38f};
  int bk[2] = {0x7FFFFFFF, 0x7FFFFFFF};

#pragma unroll 1
  for (int tt = 0; tt < 2; ++tt) {
    const int tile = kz * 2 + tt;
    __syncthreads();
#pragma unroll
    for (int j = 0; j < 8; ++j) {
      int flat = j * 256 + t;
      int row = flat >> 6, col4 = flat & 63;
      *(float4*)&cbt[row][col4 * 4] =
          *(const float4*)&emb[((size_t)cls * KC + tile * 32 + row) * DD + col4 * 4];
    }
    __syncthreads();

    v2f A2[2][2][2];
#pragma unroll
    for (int ps = 0; ps < 2; ++ps)
#pragma unroll
      for (int ks = 0; ks < 2; ++ks) {
        A2[ps][ks][0] = (v2f){0.f, 0.f};
        A2[ps][ks][1] = (v2f){0.f, 0.f};
      }

#pragma unroll 1
    for (int c16 = 0; c16 < 16; ++c16) {
      v2f za2[2][8], ca2[2][8];
#pragma unroll
      for (int q = 0; q < 4; ++q) {
        float4 z0 = *(const float4*)&zrow[pg][c16 * 16 + q * 4];
        float4 z1 = *(const float4*)&zrow[pg + 16][c16 * 16 + q * 4];
        float4 c0 = *(const float4*)&cbt[kg][c16 * 16 + q * 4];
        float4 c1 = *(const float4*)&cbt[kg + 16][c16 * 16 + q * 4];
        za2[0][q * 2 + 0] = (v2f){z0.x, z0.y};
        za2[0][q * 2 + 1] = (v2f){z0.z, z0.w};
        za2[1][q * 2 + 0] = (v2f){z1.x, z1.y};
        za2[1][q * 2 + 1] = (v2f){z1.z, z1.w};
        ca2[0][q * 2 + 0] = (v2f){c0.x, c0.y};
        ca2[0][q * 2 + 1] = (v2f){c0.z, c0.w};
        ca2[1][q * 2 + 0] = (v2f){c1.x, c1.y};
        ca2[1][q * 2 + 1] = (v2f){c1.z, c1.w};
      }
#pragma unroll
      for (int s = 3; s >= 0; --s)
#pragma unroll
        for (int ps = 0; ps < 2; ++ps)
#pragma unroll
          for (int ks = 0; ks < 2; ++ks) {
            A2[ps][ks][0] =
                pk_add(pk_mul(za2[ps][s * 2 + 0], ca2[ks][s * 2 + 0]), A2[ps][ks][0]);
            A2[ps][ks][1] =
                pk_add(pk_mul(za2[ps][s * 2 + 1], ca2[ks][s * 2 + 1]), A2[ps][ks][1]);
          }
    }

#pragma unroll
    for (int ps = 0; ps < 2; ++ps) {
      const float zqv = zq[pg + 16 * ps];
#pragma unroll
      for (int ks = 0; ks < 2; ++ks) {
        const int k = tile * 32 + kg + 16 * ks;
        float dot = (A2[ps][ks][0].x + A2[ps][ks][0].y) +
                    (A2[ps][ks][1].x + A2[ps][ks][1].y);
        float dist = (zqv - 2.0f * dot) + cbsq[cls * KC + k];
        if (dist < best[ps]) { best[ps] = dist; bk[ps] = k; }
      }
    }
  }

#pragma unroll
  for (int s = 0; s < 2; ++s) {
    __syncthreads();
    red_v[t] = best[s];
    red_k[t] = bk[s];
    __syncthreads();
    for (int off = 8; off >= 1; off >>= 1) {
      if (kg < off) {
        int o = t + 16 * off;
        float ov = red_v[o];
        int ok = red_k[o];
        if (ov < red_v[t] || (ov == red_v[t] && ok < red_k[t])) {
          red_v[t] = ov;
          red_k[t] = ok;
        }
      }
      __syncthreads();
    }
    if (kg == 0 && ((s == 0 && val0) || (s == 1 && val1))) {
      unsigned e = bn[pg + 16 * s];
      unsigned u = __float_as_uint(red_v[t]);
      u = (u & 0x80000000u) ? ~u : (u | 0x80000000u);
      u64 pkd = ((u64)u << 32) | (unsigned)red_k[t];
      atomicMin(&best_g[(e >> 12) * NP + (e & (NP - 1))], pkd);
    }
  }
}

// ---- commit: unpack merged best into idx (flagged entries only) ----
__global__ __launch_bounds__(256) void vq_commit_kernel(
    const u64* __restrict__ best_g, const unsigned int* __restrict__ counters,
    const unsigned int* __restrict__ lists, int* __restrict__ idx_out) {
  const int cls = blockIdx.x;
  unsigned cnt = counters[cls];
  if (cnt > PER_CLS) cnt = PER_CLS;
  for (unsigned i = threadIdx.x; i < cnt; i += 256) {
    unsigned e = lists[cls * PER_CLS + i];
    int pos = (int)(e >> 12) * NP + (int)(e & (NP - 1));
    u64 v = best_g[pos];
    if (v != ~0ull) idx_out[pos] = (int)(unsigned)(v & 0xFFFFFFFFu);
  }
}

// ---- gather selected rows -> [B,H,W,D] (bitwise copy; overwrites d_out) ----
__global__ __launch_bounds__(256) void vq_gather_kernel(
    const int* __restrict__ c, const float* __restrict__ emb,
    const int* __restrict__ idx, float* __restrict__ out) {
  int t = threadIdx.x;
  int r = blockIdx.x * 4 + (t >> 6);
  int lane = t & 63;
  int b = r >> 12;
  int k = idx[r];
  const float4* src = (const float4*)(emb + (size_t)(c[b] * KC + k) * DD);
  float4* dst = (float4*)(out + (size_t)r * DD);
  dst[lane] = src[lane];
}

extern "C" void kernel_launch(void* const* d_in, const int* in_sizes, int n_in,
                              void* d_out, int out_size, void* d_ws, size_t ws_size,
                              hipStream_t stream) {
  const float* z = (const float*)d_in[0];    // [32,256,64,64]
  const int* c = (const int*)d_in[1];        // [32]
  const float* emb = (const float*)d_in[2];  // [30720,256]
  float* out = (float*)d_out;                // [32,64,64,256] = 134.2 MB

  char* ws = (char*)d_ws;
  float* zsq = (float*)ws;                                   // 512 KB
  float* cbsq = (float*)(ws + 524288);                       // 120 KB
  int* idx = (int*)(ws + 655360);                            // 512 KB
  unsigned int* counters = (unsigned int*)(ws + 1179648);    // 256 B
  unsigned int* lists = (unsigned int*)(ws + 1179904);       // 480 KB

  // d_out spare: zT_h (67.1 MB) + cb_h (15.7 MB) + best_g (1 MB); gather
  // fully overwrites d_out last.
  f16* zT_h = (f16*)d_out;
  f16* cb_h = (f16*)((char*)d_out + (size_t)BB * NP * DD * 2);
  u64* best_g = (u64*)((char*)d_out + 82837504);

  hipMemsetAsync(counters, 0, NCLS * sizeof(unsigned int), stream);
  hipMemsetAsync(best_g, 0xFF, (size_t)BB * NP * 8, stream);
  vq_prep_kernel<<<ZBLOCKS + CBLOCKS, 256, 0, stream>>>(z, emb, zsq, cbsq, zT_h, cb_h);
  vq_mfma_kernel<<<ZBLOCKS, 256, 0, stream>>>(zT_h, c, cb_h, cbsq, idx, counters, lists);
  dim3 gF(NCLS, (PER_CLS / 32) * 8);
  vq_fix_kernel<<<gF, 256, 0, stream>>>(z, emb, zsq, cbsq, best_g, counters, lists);
  vq_commit_kernel<<<NCLS, 256, 0, stream>>>(best_g, counters, lists, idx);
  vq_gather_kernel<<<(BB * NP) / 4, 256, 0, stream>>>(c, emb, idx, out);
}